// Round 24
// baseline (84.259 us; speedup 1.0000x reference)
//
#include <hip/hip_runtime.h>

// DSAttention forward, MI355X gfx950.
// B=2, L=S=2048, H=16, E=D=64. fp32 in/out, fp16 MFMA compute.
//
// Round 23 (v10b): v10 (measured 77-81us) + two micro-tweaks:
//  - GLDS staging issued BEFORE the per-tile delta loads (staging in flight
//    ~40cyc earlier per iteration).
//  - setprio removed from the QK cluster (m190: null-to-negative in
//    barrier-locked loops; its ds_reads can starve co-resident waves);
//    kept on the PV cluster (m191: +4-7% attn).
// Everything else byte-identical to v10: mfma_f32_32x32x16_f16 (1 q/lane),
// PSWAP P-redistribution, split-S 8-wave blocks, 1-deep pipeline
// (K t+2 / V t+1) over GLDS-staged XOR-swizzled LDS, exp2-domain softmax,
// lane-local defer vote, lazy-l, XCD decode, flash-combine epilogue.

#define Bb 2
#define Ll 2048
#define Ss 2048
#define Hh 16
#define Ee 64
#define Dd 64
#define KV 64
#define NT 16   // (Ss/2)/KV per half

typedef _Float16 f16x8 __attribute__((ext_vector_type(8)));
typedef _Float16 f16x4 __attribute__((ext_vector_type(4)));
typedef __fp16 fp16x2 __attribute__((ext_vector_type(2)));
typedef float f32x4 __attribute__((ext_vector_type(4)));
typedef float f32x16 __attribute__((ext_vector_type(16)));

union Pk2 { fp16x2 h; unsigned u; };
union PackU { unsigned u[4]; f16x8 v; };

#define GLDS(gp, lp) __builtin_amdgcn_global_load_lds( \
    (const __attribute__((address_space(1))) void*)(gp), \
    (__attribute__((address_space(3))) void*)(lp), 16, 0, 0)

#if __has_builtin(__builtin_amdgcn_exp2f)
#define EXP2(x) __builtin_amdgcn_exp2f(x)
#else
#define EXP2(x) exp2f(x)
#endif

#define LOG2E 1.4426950408889634f

// swap x's high 32 lanes with y's low 32 lanes
#define PSWAP(x, y) asm volatile("v_permlane32_swap_b32 %0, %1" : "+v"(x), "+v"(y))

// ---- pre-pass: K fp32 [B,S,H,E] -> fp16 [B,H,S,E]; delta2 = 0.125*log2e*delta ----
__global__ __launch_bounds__(256)
void prepass_k(const float* __restrict__ K, _Float16* __restrict__ K16,
               const float* __restrict__ delta, float* __restrict__ delta2)
{
    const unsigned v = blockIdx.x * 256 + threadIdx.x;   // float4 id, 1M total
    const unsigned e4 = v & 15;
    const unsigned h  = (v >> 4) & 15;
    const unsigned s  = (v >> 8) & (Ss - 1);
    const unsigned b  = v >> 19;
    const f32x4 src = ((const f32x4*)K)[v];
    f16x4 t;
    t[0] = (_Float16)src[0]; t[1] = (_Float16)src[1];
    t[2] = (_Float16)src[2]; t[3] = (_Float16)src[3];
    ((f16x4*)K16)[(((size_t)(b * Hh + h) * Ss + s) * 16) + e4] = t;
    if (v < (Bb * Ss) / 4) {
        const float sc = 0.125f * LOG2E;
        f32x4 dd = ((const f32x4*)delta)[v];
        ((f32x4*)delta2)[v] = (f32x4){sc * dd[0], sc * dd[1], sc * dd[2], sc * dd[3]};
    }
}

// ------------- pre-pass: V fp32 [B,S,H,D] -> fp16 transposed [B,H,D,S] -------------
__global__ __launch_bounds__(256)
void prepass_v(const float* __restrict__ V, _Float16* __restrict__ VT16)
{
    __shared__ _Float16 TL[64][66];
    const int tid  = threadIdx.x;
    const int wave = tid >> 6;
    const int lane = tid & 63;
    const int bh = blockIdx.y;
    const int b  = bh >> 4;
    const int h  = bh & 15;
    const int s0 = blockIdx.x * 64;

    #pragma unroll
    for (int rr = 0; rr < 16; ++rr) {
        const int row = wave * 16 + rr;
        TL[row][lane] = (_Float16)V[((size_t)(b * Ss + s0 + row) * Hh + h) * Dd + lane];
    }
    __syncthreads();
    const int d  = tid >> 2;
    const int sq = (tid & 3) * 16;
    union { _Float16 h[16]; f16x8 v[2]; } tmp;
    #pragma unroll
    for (int i = 0; i < 16; ++i) tmp.h[i] = TL[sq + i][d];
    f16x8* dp = (f16x8*)(VT16 + ((size_t)(b * Hh + h) * Dd + d) * Ss + s0 + sq);
    dp[0] = tmp.v[0];
    dp[1] = tmp.v[1];
}

// ---------------------------- main kernel (v10b) ----------------------------
// LDS per half (32768 B at stBase): Kbuf c @ c*8192 (64rows x 128B),
// Vbuf c @ 16384 + c*8192.

#define PBODY(T, CP, CN)                                                             \
{                                                                                    \
    const int sb_ = sBase + (T) * KV;                                                \
    /* stage FIRST: K[t+2], V[t+1] into flight before anything else */               \
    if ((T) + 2 < NT) {                                                              \
        unsigned char* kw = stBase + ((T) & 1) * 8192 + wq * 1024;                   \
        GLDS(kb + (size_t)(sb_ + 2 * KV + row0) * 128 + slotS * 16, kw);             \
        GLDS(kb + (size_t)(sb_ + 2 * KV + row0 + 32) * 128 + slotS * 16, kw + 4096); \
    }                                                                                \
    if ((T) + 1 < NT) {                                                              \
        unsigned char* vw = stBase + 16384 + (((T) + 1) & 1) * 8192 + wq * 1024;     \
        GLDS(vtb + (size_t)row0 * (Ss * 2) + (sb_ + KV) * 2 + slotS * 16, vw);       \
        GLDS(vtb + (size_t)(row0 + 32) * (Ss * 2) + (sb_ + KV) * 2 + slotS * 16, vw + 4096); \
    }                                                                                \
    /* delta for THIS tile (L1/L2-hot) */                                            \
    f32x4 dreg[2][4];                                                                \
    _Pragma("unroll")                                                                \
    for (int st = 0; st < 2; ++st)                                                   \
        _Pragma("unroll")                                                            \
        for (int q4 = 0; q4 < 4; ++q4)                                               \
            dreg[st][q4] = *(const f32x4*)(d2b + sb_ + st * 32 + q4 * 8 + hl * 4);   \
    if ((T) + 1 < NT) {                                                              \
        const unsigned char* Ksm = stBase + (((T) + 1) & 1) * 8192;                  \
        _Pragma("unroll")                                                            \
        for (int st = 0; st < 2; ++st)                                               \
            _Pragma("unroll")                                                        \
            for (int i = 0; i < 16; ++i) CN[st][i] = 0.f;                            \
        _Pragma("unroll")                                                            \
        for (int st = 0; st < 2; ++st) {                                             \
            const int krow = st * 32 + c31;                                          \
            _Pragma("unroll")                                                        \
            for (int es = 0; es < 4; ++es) {                                         \
                const int slot = (es * 2 + hl) ^ (krow & 7);                         \
                f16x8 ak = *(const f16x8*)(Ksm + krow * 128 + slot * 16);            \
                CN[st] = __builtin_amdgcn_mfma_f32_32x32x16_f16(ak, aq[es], CN[st], 0, 0, 0); \
            }                                                                        \
        }                                                                            \
    }                                                                                \
    const unsigned char* Vsm = stBase + 16384 + ((T) & 1) * 8192;                    \
    _Pragma("unroll")                                                                \
    for (int st = 0; st < 2; ++st) {                                                 \
        float p[16];                                                                 \
        _Pragma("unroll")                                                            \
        for (int q4 = 0; q4 < 4; ++q4)                                               \
            _Pragma("unroll")                                                        \
            for (int j = 0; j < 4; ++j)                                              \
                p[q4 * 4 + j] = fmaf(alpha2, CP[st][q4 * 4 + j], dreg[st][q4][j]);   \
        float x0 = fmaxf(p[0], p[1]),  x1 = fmaxf(p[2], p[3]);                       \
        float x2 = fmaxf(p[4], p[5]),  x3 = fmaxf(p[6], p[7]);                       \
        float x4 = fmaxf(p[8], p[9]),  x5 = fmaxf(p[10], p[11]);                     \
        float x6 = fmaxf(p[12], p[13]), x7 = fmaxf(p[14], p[15]);                    \
        x0 = fmaxf(x0, x1); x2 = fmaxf(x2, x3); x4 = fmaxf(x4, x5); x6 = fmaxf(x6, x7); \
        const float tmax = fmaxf(fmaxf(x0, x2), fmaxf(x4, x6));                      \
        if (!__all(tmax <= m_run + 11.5416f)) {                                      \
            float rmax = fmaxf(tmax, __shfl_xor(tmax, 32));                          \
            const float m_new = fmaxf(m_run, rmax);                                  \
            const float corr = EXP2(m_run - m_new);                                  \
            l_run *= corr;                                                           \
            _Pragma("unroll")                                                        \
            for (int dt = 0; dt < 2; ++dt)                                           \
                _Pragma("unroll")                                                    \
                for (int i = 0; i < 16; ++i) osum[dt][i] *= corr;                    \
            m_run = m_new;                                                           \
        }                                                                            \
        _Pragma("unroll")                                                            \
        for (int i = 0; i < 16; ++i) p[i] = EXP2(p[i] - m_run);                      \
        {                                                                            \
            float s0 = p[0] + p[1],  s1 = p[2] + p[3];                               \
            float s2 = p[4] + p[5],  s3 = p[6] + p[7];                               \
            float s4 = p[8] + p[9],  s5 = p[10] + p[11];                             \
            float s6 = p[12] + p[13], s7 = p[14] + p[15];                            \
            s0 += s1; s2 += s3; s4 += s5; s6 += s7;                                  \
            l_run += (s0 + s2) + (s4 + s6);                                          \
        }                                                                            \
        /* pack: pk[2t+i] = fp16(p[4t+2i], p[4t+2i+1]) = s-pair (8t+4hl+2i,+1) */    \
        unsigned pk[8];                                                              \
        _Pragma("unroll")                                                            \
        for (int t4 = 0; t4 < 4; ++t4) {                                             \
            Pk2 u0, u1;                                                              \
            u0.h = __builtin_amdgcn_cvt_pkrtz(p[4 * t4], p[4 * t4 + 1]);             \
            u1.h = __builtin_amdgcn_cvt_pkrtz(p[4 * t4 + 2], p[4 * t4 + 3]);         \
            pk[t4 * 2] = u0.u;                                                       \
            pk[t4 * 2 + 1] = u1.u;                                                   \
        }                                                                            \
        __builtin_amdgcn_s_setprio(1);                                               \
        _Pragma("unroll")                                                            \
        for (int ks = 0; ks < 2; ++ks) {                                             \
            unsigned b0 = pk[ks * 4 + 0], b1 = pk[ks * 4 + 1];                       \
            unsigned b2 = pk[ks * 4 + 2], b3 = pk[ks * 4 + 3];                       \
            PSWAP(b0, b2);                                                           \
            PSWAP(b1, b3);                                                           \
            PackU bf;                                                                \
            bf.u[0] = b0; bf.u[1] = b1; bf.u[2] = b2; bf.u[3] = b3;                  \
            _Pragma("unroll")                                                        \
            for (int dt = 0; dt < 2; ++dt) {                                         \
                const int vrow = dt * 32 + c31;                                      \
                const int slot = (st * 4 + ks * 2 + hl) ^ (vrow & 7);                \
                f16x8 av = *(const f16x8*)(Vsm + vrow * 128 + slot * 16);            \
                osum[dt] = __builtin_amdgcn_mfma_f32_32x32x16_f16(av, bf.v, osum[dt], 0, 0, 0); \
            }                                                                        \
        }                                                                            \
        __builtin_amdgcn_s_setprio(0);                                               \
    }                                                                                \
    __syncthreads();                                                                 \
}

__global__ __launch_bounds__(512)
void dsattn_fwd_v10(const float* __restrict__ Q, const _Float16* __restrict__ K16,
                    const _Float16* __restrict__ VT16, const float* __restrict__ tau,
                    const float* __restrict__ delta2, float* __restrict__ out)
{
    extern __shared__ __align__(16) unsigned char smem[];

    const int tid  = threadIdx.x;
    const int wave = tid >> 6;        // 0..7
    const int halfId = wave >> 2;     // s-half
    const int wq   = wave & 3;        // q-quarter within block
    const int lane = tid & 63;
    const int c31  = lane & 31;       // this lane's q column / matrix row index
    const int hl   = lane >> 5;       // lane half
    const int tid_h = tid & 255;      // id within the half's staging group

    // XCD-aware decode: block i -> XCD i&7; XCD j owns bh {4j..4j+3}.
    const int bid = blockIdx.x;       // 0..511
    const int xcd = bid & 7;
    const int kk  = bid >> 3;         // 0..63
    const int bh  = xcd * 4 + (kk & 3);
    const int b   = bh >> 4;
    const int hd  = bh & 15;
    const int q0  = (kk >> 2) * 128;  // q-block 0..15
    const int qw  = q0 + wq * 32;     // wave covers 32 q

    const float alpha2 = 0.125f * LOG2E * tau[b];

    // Q fragments (B operand): lane holds Q[qw + c31][es*16 + hl*8 + j]
    f16x8 aq[4];
    {
        const float* qp = Q + (((size_t)b * Ll + qw + c31) * Hh + hd) * Ee;
        #pragma unroll
        for (int es = 0; es < 4; ++es) {
            const float* p = qp + es * 16 + hl * 8;
            f16x8 t;
            #pragma unroll
            for (int j = 0; j < 8; ++j) t[j] = (_Float16)p[j];
            aq[es] = t;
        }
    }

    f32x16 osum[2];
    #pragma unroll
    for (int dt = 0; dt < 2; ++dt)
        #pragma unroll
        for (int i = 0; i < 16; ++i) osum[dt][i] = 0.f;
    float m_run = -1e30f;
    float l_run = 0.0f;               // per-lane partial (lazy reduction)

    const unsigned char* kb  = (const unsigned char*)(K16 + (size_t)(b * Hh + hd) * Ss * Ee);
    const unsigned char* vtb = (const unsigned char*)(VT16 + (size_t)(b * Hh + hd) * Dd * Ss);
    const float* d2b = delta2 + (size_t)b * Ss;

    const int row0  = tid_h >> 3;                     // 0..31; issue 1 = +32
    const int slotS = (tid_h & 7) ^ (row0 & 7);
    unsigned char* stBase = smem + halfId * 32768;
    const int sBase = halfId * (Ss / 2);

    // ---- prologue: K[0]->Kbuf0, V[0]->Vbuf0, K[1]->Kbuf1; QK(0) ----
    {
        unsigned char* kw0 = stBase + wq * 1024;
        GLDS(kb + (size_t)(sBase + row0) * 128 + slotS * 16, kw0);
        GLDS(kb + (size_t)(sBase + row0 + 32) * 128 + slotS * 16, kw0 + 4096);
        unsigned char* vw0 = stBase + 16384 + wq * 1024;
        GLDS(vtb + (size_t)row0 * (Ss * 2) + sBase * 2 + slotS * 16, vw0);
        GLDS(vtb + (size_t)(row0 + 32) * (Ss * 2) + sBase * 2 + slotS * 16, vw0 + 4096);
        unsigned char* kw1 = stBase + 8192 + wq * 1024;
        GLDS(kb + (size_t)(sBase + KV + row0) * 128 + slotS * 16, kw1);
        GLDS(kb + (size_t)(sBase + KV + row0 + 32) * 128 + slotS * 16, kw1 + 4096);
    }
    __syncthreads();   // Kbuf0/Kbuf1/Vbuf0 ready

    f32x16 cA[2], cB[2];
    #pragma unroll
    for (int st = 0; st < 2; ++st)
        #pragma unroll
        for (int i = 0; i < 16; ++i) cA[st][i] = 0.f;
    {
        const unsigned char* Ksm = stBase;   // Kbuf0
        #pragma unroll
        for (int st = 0; st < 2; ++st) {
            const int krow = st * 32 + c31;
            #pragma unroll
            for (int es = 0; es < 4; ++es) {
                const int slot = (es * 2 + hl) ^ (krow & 7);
                f16x8 ak = *(const f16x8*)(Ksm + krow * 128 + slot * 16);
                cA[st] = __builtin_amdgcn_mfma_f32_32x32x16_f16(ak, aq[es], cA[st], 0, 0, 0);
            }
        }
    }
    __syncthreads();   // all waves done reading Kbuf0 before BODY(0) stages K[2]

    for (int t = 0; t < NT; t += 2) {
        PBODY(t,     cA, cB);
        PBODY(t + 1, cB, cA);
    }

    // ---- finalize per-lane l partial -> per-q total (one swap) ----
    l_run += __shfl_xor(l_run, 32);

    // ---- epilogue: flash-combine the two s-halves, then coalesced store ----
    float (*Part)[32][68] = (float (*)[32][68])smem;   // [4][32][68] = 34816 B
    if (halfId == 1) {
        #pragma unroll
        for (int dt = 0; dt < 2; ++dt)
            #pragma unroll
            for (int q4 = 0; q4 < 4; ++q4) {
                f32x4 v = (f32x4){osum[dt][q4 * 4], osum[dt][q4 * 4 + 1],
                                  osum[dt][q4 * 4 + 2], osum[dt][q4 * 4 + 3]};
                *(f32x4*)&Part[wq][c31][dt * 32 + q4 * 8 + hl * 4] = v;
            }
        if (hl == 0) {
            Part[wq][c31][64] = m_run;
            Part[wq][c31][65] = l_run;
        }
    }
    __syncthreads();
    if (halfId == 0) {
        const float m1 = Part[wq][c31][64];
        const float l1 = Part[wq][c31][65];
        const float m  = fmaxf(m_run, m1);
        const float s0 = EXP2(m_run - m);
        const float s1 = EXP2(m1 - m);
        const float inv = 1.0f / (l_run * s0 + l1 * s1);
        #pragma unroll
        for (int dt = 0; dt < 2; ++dt)
            #pragma unroll
            for (int q4 = 0; q4 < 4; ++q4) {
                f32x4 p1 = *(const f32x4*)&Part[wq][c31][dt * 32 + q4 * 8 + hl * 4];
                #pragma unroll
                for (int j = 0; j < 4; ++j)
                    osum[dt][q4 * 4 + j] = (osum[dt][q4 * 4 + j] * s0 + p1[j] * s1) * inv;
            }
    }
    __syncthreads();   // all Part reads done; smem reusable
    float (*Osm)[68] = (float (*)[68])smem;            // [128][68] = 34816 B
    if (halfId == 0) {
        #pragma unroll
        for (int dt = 0; dt < 2; ++dt)
            #pragma unroll
            for (int q4 = 0; q4 < 4; ++q4) {
                f32x4 v = (f32x4){osum[dt][q4 * 4], osum[dt][q4 * 4 + 1],
                                  osum[dt][q4 * 4 + 2], osum[dt][q4 * 4 + 3]};
                *(f32x4*)&Osm[wq * 32 + c31][dt * 32 + q4 * 8 + hl * 4] = v;
            }
    }
    __syncthreads();
    {
        float* ob = out + (((size_t)b * Ll + q0) * Hh + hd) * Dd;
        #pragma unroll
        for (int i = 0; i < 16; ++i) {
            const int r = wave * 16 + i;
            ob[(size_t)r * (Hh * Dd) + lane] = Osm[r][lane];
        }
    }
}

// ---------------------------- fallback (v1, verified r5) ----------------------------
__global__ __launch_bounds__(256)
void dsattn_fwd(const float* __restrict__ Q, const float* __restrict__ K,
                const float* __restrict__ V, const float* __restrict__ tau,
                const float* __restrict__ delta, float* __restrict__ out)
{
    __shared__ __align__(16) unsigned char Ksm[32 * 128];
    __shared__ __align__(16) unsigned char VTsm[64 * 80];
    __shared__ float dsm[32];
    __shared__ float Osm[4][16][68];

    const int tid  = threadIdx.x;
    const int wave = tid >> 6;
    const int lane = tid & 63;
    const int lq   = lane & 15;
    const int g    = lane >> 4;

    const int bh = blockIdx.y;
    const int b  = bh >> 4;
    const int h  = bh & 15;
    const int q0 = blockIdx.x * 64;

    const float alpha = 0.125f * tau[b];

    f16x8 aq[2];
    {
        const float* qp = Q + (((long)b * Ll + q0 + wave * 16 + lq) * Hh + h) * Ee;
        #pragma unroll
        for (int es = 0; es < 2; ++es) {
            const float* p = qp + es * 32 + g * 8;
            f16x8 t;
            #pragma unroll
            for (int j = 0; j < 8; ++j) t[j] = (_Float16)p[j];
            aq[es] = t;
        }
    }

    f32x4 osum[4];
    #pragma unroll
    for (int i = 0; i < 4; ++i) osum[i] = (f32x4){0.f, 0.f, 0.f, 0.f};
    float m_run = -1e30f, l_run = 0.0f;

    const float* kb = K + ((long)b * Ss * Hh + h) * Ee;
    const float* vb = V + ((long)b * Ss * Hh + h) * Dd;
    const float* db = delta + (long)b * Ss;

    const int kr    = tid >> 3;
    const int kc    = (tid & 7) * 8;
    const int kslot = (((tid & 7) ^ (kr & 7)) * 16);
    const int vd    = tid & 63;
    const int vsh   = tid >> 6;

    for (int sb = 0; sb < Ss; sb += 32) {
        __syncthreads();
        {
            const float* src = kb + (long)(sb + kr) * (Hh * Ee) + kc;
            f16x8 t;
            #pragma unroll
            for (int j = 0; j < 8; ++j) t[j] = (_Float16)src[j];
            *(f16x8*)(Ksm + kr * 128 + kslot) = t;
        }
        {
            const float* src = vb + (long)(sb + vsh * 8) * (Hh * Dd) + vd;
            f16x8 t;
            #pragma unroll
            for (int j = 0; j < 8; ++j) t[j] = (_Float16)src[j * (Hh * Dd)];
            *(f16x8*)(VTsm + vd * 80 + vsh * 16) = t;
        }
        if (tid < 32) dsm[tid] = 0.125f * db[sb + tid];
        __syncthreads();

        float p[8];
        float tmax = -1e30f;
        #pragma unroll
        for (int t = 0; t < 2; ++t) {
            f32x4 c = (f32x4){0.f, 0.f, 0.f, 0.f};
            #pragma unroll
            for (int es = 0; es < 2; ++es) {
                const int srow = t * 16 + lq;
                const int slot = ((es * 4 + g) ^ (srow & 7)) * 16;
                f16x8 ak = *(const f16x8*)(Ksm + srow * 128 + slot);
                c = __builtin_amdgcn_mfma_f32_16x16x32_f16(ak, aq[es], c, 0, 0, 0);
            }
            #pragma unroll
            for (int j = 0; j < 4; ++j) {
                float z = alpha * c[j] + dsm[t * 16 + 4 * g + j];
                p[t * 4 + j] = z;
                tmax = fmaxf(tmax, z);
            }
        }
        tmax = fmaxf(tmax, __shfl_xor(tmax, 16));
        tmax = fmaxf(tmax, __shfl_xor(tmax, 32));
        const float m_new = fmaxf(m_run, tmax);
        const float corr  = __expf(m_run - m_new);
        float psum = 0.f;
        #pragma unroll
        for (int i = 0; i < 8; ++i) { p[i] = __expf(p[i] - m_new); psum += p[i]; }
        psum += __shfl_xor(psum, 16);
        psum += __shfl_xor(psum, 32);
        l_run = l_run * corr + psum;
        m_run = m_new;
        #pragma unroll
        for (int dt = 0; dt < 4; ++dt)
            #pragma unroll
            for (int j = 0; j < 4; ++j)
                osum[dt][j] *= corr;

        Pk2 u00, u01, u10, u11;
        u00.h = __builtin_amdgcn_cvt_pkrtz(p[0], p[1]);
        u01.h = __builtin_amdgcn_cvt_pkrtz(p[2], p[3]);
        u10.h = __builtin_amdgcn_cvt_pkrtz(p[4], p[5]);
        u11.h = __builtin_amdgcn_cvt_pkrtz(p[6], p[7]);
        const int srcA = lq + 32 * (g & 1);
        const int srcB = srcA + 16;
        unsigned a00 = __shfl(u00.u, srcA), a01 = __shfl(u01.u, srcA);
        unsigned a10 = __shfl(u10.u, srcA), a11 = __shfl(u11.u, srcA);
        unsigned b00 = __shfl(u00.u, srcB), b01 = __shfl(u01.u, srcB);
        unsigned b10 = __shfl(u10.u, srcB), b11 = __shfl(u11.u, srcB);
        const bool hi = (g >= 2);
        PackU bp;
        bp.u[0] = hi ? a10 : a00;
        bp.u[1] = hi ? a11 : a01;
        bp.u[2] = hi ? b10 : b00;
        bp.u[3] = hi ? b11 : b01;

        #pragma unroll
        for (int dt = 0; dt < 4; ++dt) {
            f16x8 av = *(const f16x8*)(VTsm + (dt * 16 + lq) * 80 + g * 16);
            osum[dt] = __builtin_amdgcn_mfma_f32_16x16x32_f16(av, bp.v, osum[dt], 0, 0, 0);
        }
    }

    const float inv = 1.0f / l_run;
    #pragma unroll
    for (int dt = 0; dt < 4; ++dt)
        #pragma unroll
        for (int j = 0; j < 4; ++j)
            Osm[wave][lq][dt * 16 + 4 * g + j] = osum[dt][j] * inv;
    __syncthreads();
    {
        float* ob = out + (((long)b * Ll + q0 + wave * 16) * Hh + h) * Dd;
        #pragma unroll
        for (int r = 0; r < 16; ++r)
            ob[(long)r * (Hh * Dd) + lane] = Osm[wave][r][lane];
    }
}

extern "C" void kernel_launch(void* const* d_in, const int* in_sizes, int n_in,
                              void* d_out, int out_size, void* d_ws, size_t ws_size,
                              hipStream_t stream) {
    const float* Q     = (const float*)d_in[0];
    const float* K     = (const float*)d_in[1];
    const float* V     = (const float*)d_in[2];
    const float* tau   = (const float*)d_in[3];
    const float* delta = (const float*)d_in[4];
    float* out = (float*)d_out;

    const size_t elems = (size_t)Bb * Hh * Ss * Ee;            // 4M per tensor
    const size_t need  = elems * 2 * 2 + (size_t)Bb * Ss * 4;  // K16 + VT16 + delta2

    if (ws_size >= need) {
        _Float16* K16    = (_Float16*)d_ws;
        _Float16* VT16   = K16 + elems;
        float*    delta2 = (float*)(VT16 + elems);
        hipLaunchKernelGGL(prepass_k, dim3(elems / 4 / 256), dim3(256), 0, stream,
                           K, K16, delta, delta2);
        hipLaunchKernelGGL(prepass_v, dim3(Ss / 64, Bb * Hh), dim3(256), 0, stream, V, VT16);
        hipLaunchKernelGGL(dsattn_fwd_v10, dim3(512), dim3(512), 65536, stream,
                           Q, K16, VT16, tau, delta2, out);
    } else {
        hipLaunchKernelGGL(dsattn_fwd, dim3(Ll / 64, Bb * Hh), dim3(256), 0, stream,
                           Q, K, V, tau, delta, out);
    }
}

// Round 25
// 80.365 us; speedup vs baseline: 1.0485x; 1.0485x over previous
//
#include <hip/hip_runtime.h>

// DSAttention forward, MI355X gfx950.
// B=2, L=S=2048, H=16, E=D=64. fp32 in/out, fp16 MFMA compute.
//
// FINAL (v10, measured 77-81.5us across r20/r23; best of 12 structural
// variants over 24 rounds; baseline 117us):
//  - Pre-pass: K -> fp16 [B,H,S,E]; V -> fp16 transposed [B,H,D,S];
//    delta2 = 0.125*log2e*delta (exp2-domain).
//  - mfma_f32_32x32x16_f16, 1 q per lane (col = lane&31); C/D row map
//    (reg&3)+8*(reg>>2)+4*(lane>>5).
//  - P^T -> PV B-fragment redistribution via v_permlane32_swap_b32 (8/iter).
//  - Split-S 8-wave blocks (waves 0-3: s<1024, 4-7: s>=1024), flash-combine
//    epilogue through LDS.
//  - 1-deep pipeline: stage K[t+2]/V[t+1] via global_load_lds into
//    XOR-swizzled double-buffered LDS while computing tile t; QK^T(t+1)
//    overlaps softmax(t) via A/B accumulator sets.
//  - exp2-domain softmax, lane-local defer-max vote (THR=8*log2e), lazy
//    per-lane l reduction (combined once at epilogue).
//  - XCD-aware block decode (block i -> XCD i&7 owns bh {4(i&7)..4(i&7)+3}):
//    per-XCD K/V working set 2MB < 4MB L2 (FETCH 74->17MB).

#define Bb 2
#define Ll 2048
#define Ss 2048
#define Hh 16
#define Ee 64
#define Dd 64
#define KV 64
#define NT 16   // (Ss/2)/KV per half

typedef _Float16 f16x8 __attribute__((ext_vector_type(8)));
typedef _Float16 f16x4 __attribute__((ext_vector_type(4)));
typedef __fp16 fp16x2 __attribute__((ext_vector_type(2)));
typedef float f32x4 __attribute__((ext_vector_type(4)));
typedef float f32x16 __attribute__((ext_vector_type(16)));

union Pk2 { fp16x2 h; unsigned u; };
union PackU { unsigned u[4]; f16x8 v; };

#define GLDS(gp, lp) __builtin_amdgcn_global_load_lds( \
    (const __attribute__((address_space(1))) void*)(gp), \
    (__attribute__((address_space(3))) void*)(lp), 16, 0, 0)

#if __has_builtin(__builtin_amdgcn_exp2f)
#define EXP2(x) __builtin_amdgcn_exp2f(x)
#else
#define EXP2(x) exp2f(x)
#endif

#define LOG2E 1.4426950408889634f

// swap x's high 32 lanes with y's low 32 lanes
#define PSWAP(x, y) asm volatile("v_permlane32_swap_b32 %0, %1" : "+v"(x), "+v"(y))

// ---- pre-pass: K fp32 [B,S,H,E] -> fp16 [B,H,S,E]; delta2 = 0.125*log2e*delta ----
__global__ __launch_bounds__(256)
void prepass_k(const float* __restrict__ K, _Float16* __restrict__ K16,
               const float* __restrict__ delta, float* __restrict__ delta2)
{
    const unsigned v = blockIdx.x * 256 + threadIdx.x;   // float4 id, 1M total
    const unsigned e4 = v & 15;
    const unsigned h  = (v >> 4) & 15;
    const unsigned s  = (v >> 8) & (Ss - 1);
    const unsigned b  = v >> 19;
    const f32x4 src = ((const f32x4*)K)[v];
    f16x4 t;
    t[0] = (_Float16)src[0]; t[1] = (_Float16)src[1];
    t[2] = (_Float16)src[2]; t[3] = (_Float16)src[3];
    ((f16x4*)K16)[(((size_t)(b * Hh + h) * Ss + s) * 16) + e4] = t;
    if (v < (Bb * Ss) / 4) {
        const float sc = 0.125f * LOG2E;
        f32x4 dd = ((const f32x4*)delta)[v];
        ((f32x4*)delta2)[v] = (f32x4){sc * dd[0], sc * dd[1], sc * dd[2], sc * dd[3]};
    }
}

// ------------- pre-pass: V fp32 [B,S,H,D] -> fp16 transposed [B,H,D,S] -------------
__global__ __launch_bounds__(256)
void prepass_v(const float* __restrict__ V, _Float16* __restrict__ VT16)
{
    __shared__ _Float16 TL[64][66];
    const int tid  = threadIdx.x;
    const int wave = tid >> 6;
    const int lane = tid & 63;
    const int bh = blockIdx.y;
    const int b  = bh >> 4;
    const int h  = bh & 15;
    const int s0 = blockIdx.x * 64;

    #pragma unroll
    for (int rr = 0; rr < 16; ++rr) {
        const int row = wave * 16 + rr;
        TL[row][lane] = (_Float16)V[((size_t)(b * Ss + s0 + row) * Hh + h) * Dd + lane];
    }
    __syncthreads();
    const int d  = tid >> 2;
    const int sq = (tid & 3) * 16;
    union { _Float16 h[16]; f16x8 v[2]; } tmp;
    #pragma unroll
    for (int i = 0; i < 16; ++i) tmp.h[i] = TL[sq + i][d];
    f16x8* dp = (f16x8*)(VT16 + ((size_t)(b * Hh + h) * Dd + d) * Ss + s0 + sq);
    dp[0] = tmp.v[0];
    dp[1] = tmp.v[1];
}

// ---------------------------- main kernel (v10) ----------------------------
// LDS per half (32768 B at stBase): Kbuf c @ c*8192 (64rows x 128B),
// Vbuf c @ 16384 + c*8192.

#define PBODY(T, CP, CN)                                                             \
{                                                                                    \
    const int sb_ = sBase + (T) * KV;                                                \
    /* delta for THIS tile, loaded early (L1/L2-hot) */                              \
    f32x4 dreg[2][4];                                                                \
    _Pragma("unroll")                                                                \
    for (int st = 0; st < 2; ++st)                                                   \
        _Pragma("unroll")                                                            \
        for (int q4 = 0; q4 < 4; ++q4)                                               \
            dreg[st][q4] = *(const f32x4*)(d2b + sb_ + st * 32 + q4 * 8 + hl * 4);   \
    if ((T) + 2 < NT) {                                                              \
        unsigned char* kw = stBase + ((T) & 1) * 8192 + wq * 1024;                   \
        GLDS(kb + (size_t)(sb_ + 2 * KV + row0) * 128 + slotS * 16, kw);             \
        GLDS(kb + (size_t)(sb_ + 2 * KV + row0 + 32) * 128 + slotS * 16, kw + 4096); \
    }                                                                                \
    if ((T) + 1 < NT) {                                                              \
        unsigned char* vw = stBase + 16384 + (((T) + 1) & 1) * 8192 + wq * 1024;     \
        GLDS(vtb + (size_t)row0 * (Ss * 2) + (sb_ + KV) * 2 + slotS * 16, vw);       \
        GLDS(vtb + (size_t)(row0 + 32) * (Ss * 2) + (sb_ + KV) * 2 + slotS * 16, vw + 4096); \
        const unsigned char* Ksm = stBase + (((T) + 1) & 1) * 8192;                  \
        _Pragma("unroll")                                                            \
        for (int st = 0; st < 2; ++st)                                               \
            _Pragma("unroll")                                                        \
            for (int i = 0; i < 16; ++i) CN[st][i] = 0.f;                            \
        __builtin_amdgcn_s_setprio(1);                                               \
        _Pragma("unroll")                                                            \
        for (int st = 0; st < 2; ++st) {                                             \
            const int krow = st * 32 + c31;                                          \
            _Pragma("unroll")                                                        \
            for (int es = 0; es < 4; ++es) {                                         \
                const int slot = (es * 2 + hl) ^ (krow & 7);                         \
                f16x8 ak = *(const f16x8*)(Ksm + krow * 128 + slot * 16);            \
                CN[st] = __builtin_amdgcn_mfma_f32_32x32x16_f16(ak, aq[es], CN[st], 0, 0, 0); \
            }                                                                        \
        }                                                                            \
        __builtin_amdgcn_s_setprio(0);                                               \
    }                                                                                \
    const unsigned char* Vsm = stBase + 16384 + ((T) & 1) * 8192;                    \
    _Pragma("unroll")                                                                \
    for (int st = 0; st < 2; ++st) {                                                 \
        float p[16];                                                                 \
        _Pragma("unroll")                                                            \
        for (int q4 = 0; q4 < 4; ++q4)                                               \
            _Pragma("unroll")                                                        \
            for (int j = 0; j < 4; ++j)                                              \
                p[q4 * 4 + j] = fmaf(alpha2, CP[st][q4 * 4 + j], dreg[st][q4][j]);   \
        float x0 = fmaxf(p[0], p[1]),  x1 = fmaxf(p[2], p[3]);                       \
        float x2 = fmaxf(p[4], p[5]),  x3 = fmaxf(p[6], p[7]);                       \
        float x4 = fmaxf(p[8], p[9]),  x5 = fmaxf(p[10], p[11]);                     \
        float x6 = fmaxf(p[12], p[13]), x7 = fmaxf(p[14], p[15]);                    \
        x0 = fmaxf(x0, x1); x2 = fmaxf(x2, x3); x4 = fmaxf(x4, x5); x6 = fmaxf(x6, x7); \
        const float tmax = fmaxf(fmaxf(x0, x2), fmaxf(x4, x6));                      \
        if (!__all(tmax <= m_run + 11.5416f)) {                                      \
            float rmax = fmaxf(tmax, __shfl_xor(tmax, 32));                          \
            const float m_new = fmaxf(m_run, rmax);                                  \
            const float corr = EXP2(m_run - m_new);                                  \
            l_run *= corr;                                                           \
            _Pragma("unroll")                                                        \
            for (int dt = 0; dt < 2; ++dt)                                           \
                _Pragma("unroll")                                                    \
                for (int i = 0; i < 16; ++i) osum[dt][i] *= corr;                    \
            m_run = m_new;                                                           \
        }                                                                            \
        _Pragma("unroll")                                                            \
        for (int i = 0; i < 16; ++i) p[i] = EXP2(p[i] - m_run);                      \
        {                                                                            \
            float s0 = p[0] + p[1],  s1 = p[2] + p[3];                               \
            float s2 = p[4] + p[5],  s3 = p[6] + p[7];                               \
            float s4 = p[8] + p[9],  s5 = p[10] + p[11];                             \
            float s6 = p[12] + p[13], s7 = p[14] + p[15];                            \
            s0 += s1; s2 += s3; s4 += s5; s6 += s7;                                  \
            l_run += (s0 + s2) + (s4 + s6);                                          \
        }                                                                            \
        /* pack: pk[2t+i] = fp16(p[4t+2i], p[4t+2i+1]) = s-pair (8t+4hl+2i,+1) */    \
        unsigned pk[8];                                                              \
        _Pragma("unroll")                                                            \
        for (int t4 = 0; t4 < 4; ++t4) {                                             \
            Pk2 u0, u1;                                                              \
            u0.h = __builtin_amdgcn_cvt_pkrtz(p[4 * t4], p[4 * t4 + 1]);             \
            u1.h = __builtin_amdgcn_cvt_pkrtz(p[4 * t4 + 2], p[4 * t4 + 3]);         \
            pk[t4 * 2] = u0.u;                                                       \
            pk[t4 * 2 + 1] = u1.u;                                                   \
        }                                                                            \
        __builtin_amdgcn_s_setprio(1);                                               \
        _Pragma("unroll")                                                            \
        for (int ks = 0; ks < 2; ++ks) {                                             \
            unsigned b0 = pk[ks * 4 + 0], b1 = pk[ks * 4 + 1];                       \
            unsigned b2 = pk[ks * 4 + 2], b3 = pk[ks * 4 + 3];                       \
            PSWAP(b0, b2);                                                           \
            PSWAP(b1, b3);                                                           \
            PackU bf;                                                                \
            bf.u[0] = b0; bf.u[1] = b1; bf.u[2] = b2; bf.u[3] = b3;                  \
            _Pragma("unroll")                                                        \
            for (int dt = 0; dt < 2; ++dt) {                                         \
                const int vrow = dt * 32 + c31;                                      \
                const int slot = (st * 4 + ks * 2 + hl) ^ (vrow & 7);                \
                f16x8 av = *(const f16x8*)(Vsm + vrow * 128 + slot * 16);            \
                osum[dt] = __builtin_amdgcn_mfma_f32_32x32x16_f16(av, bf.v, osum[dt], 0, 0, 0); \
            }                                                                        \
        }                                                                            \
        __builtin_amdgcn_s_setprio(0);                                               \
    }                                                                                \
    __syncthreads();                                                                 \
}

__global__ __launch_bounds__(512)
void dsattn_fwd_v10(const float* __restrict__ Q, const _Float16* __restrict__ K16,
                    const _Float16* __restrict__ VT16, const float* __restrict__ tau,
                    const float* __restrict__ delta2, float* __restrict__ out)
{
    extern __shared__ __align__(16) unsigned char smem[];

    const int tid  = threadIdx.x;
    const int wave = tid >> 6;        // 0..7
    const int halfId = wave >> 2;     // s-half
    const int wq   = wave & 3;        // q-quarter within block
    const int lane = tid & 63;
    const int c31  = lane & 31;       // this lane's q column / matrix row index
    const int hl   = lane >> 5;       // lane half
    const int tid_h = tid & 255;      // id within the half's staging group

    // XCD-aware decode: block i -> XCD i&7; XCD j owns bh {4j..4j+3}.
    const int bid = blockIdx.x;       // 0..511
    const int xcd = bid & 7;
    const int kk  = bid >> 3;         // 0..63
    const int bh  = xcd * 4 + (kk & 3);
    const int b   = bh >> 4;
    const int hd  = bh & 15;
    const int q0  = (kk >> 2) * 128;  // q-block 0..15
    const int qw  = q0 + wq * 32;     // wave covers 32 q

    const float alpha2 = 0.125f * LOG2E * tau[b];

    // Q fragments (B operand): lane holds Q[qw + c31][es*16 + hl*8 + j]
    f16x8 aq[4];
    {
        const float* qp = Q + (((size_t)b * Ll + qw + c31) * Hh + hd) * Ee;
        #pragma unroll
        for (int es = 0; es < 4; ++es) {
            const float* p = qp + es * 16 + hl * 8;
            f16x8 t;
            #pragma unroll
            for (int j = 0; j < 8; ++j) t[j] = (_Float16)p[j];
            aq[es] = t;
        }
    }

    f32x16 osum[2];
    #pragma unroll
    for (int dt = 0; dt < 2; ++dt)
        #pragma unroll
        for (int i = 0; i < 16; ++i) osum[dt][i] = 0.f;
    float m_run = -1e30f;
    float l_run = 0.0f;               // per-lane partial (lazy reduction)

    const unsigned char* kb  = (const unsigned char*)(K16 + (size_t)(b * Hh + hd) * Ss * Ee);
    const unsigned char* vtb = (const unsigned char*)(VT16 + (size_t)(b * Hh + hd) * Dd * Ss);
    const float* d2b = delta2 + (size_t)b * Ss;

    const int row0  = tid_h >> 3;                     // 0..31; issue 1 = +32
    const int slotS = (tid_h & 7) ^ (row0 & 7);
    unsigned char* stBase = smem + halfId * 32768;
    const int sBase = halfId * (Ss / 2);

    // ---- prologue: K[0]->Kbuf0, V[0]->Vbuf0, K[1]->Kbuf1; QK(0) ----
    {
        unsigned char* kw0 = stBase + wq * 1024;
        GLDS(kb + (size_t)(sBase + row0) * 128 + slotS * 16, kw0);
        GLDS(kb + (size_t)(sBase + row0 + 32) * 128 + slotS * 16, kw0 + 4096);
        unsigned char* vw0 = stBase + 16384 + wq * 1024;
        GLDS(vtb + (size_t)row0 * (Ss * 2) + sBase * 2 + slotS * 16, vw0);
        GLDS(vtb + (size_t)(row0 + 32) * (Ss * 2) + sBase * 2 + slotS * 16, vw0 + 4096);
        unsigned char* kw1 = stBase + 8192 + wq * 1024;
        GLDS(kb + (size_t)(sBase + KV + row0) * 128 + slotS * 16, kw1);
        GLDS(kb + (size_t)(sBase + KV + row0 + 32) * 128 + slotS * 16, kw1 + 4096);
    }
    __syncthreads();   // Kbuf0/Kbuf1/Vbuf0 ready

    f32x16 cA[2], cB[2];
    #pragma unroll
    for (int st = 0; st < 2; ++st)
        #pragma unroll
        for (int i = 0; i < 16; ++i) cA[st][i] = 0.f;
    {
        const unsigned char* Ksm = stBase;   // Kbuf0
        #pragma unroll
        for (int st = 0; st < 2; ++st) {
            const int krow = st * 32 + c31;
            #pragma unroll
            for (int es = 0; es < 4; ++es) {
                const int slot = (es * 2 + hl) ^ (krow & 7);
                f16x8 ak = *(const f16x8*)(Ksm + krow * 128 + slot * 16);
                cA[st] = __builtin_amdgcn_mfma_f32_32x32x16_f16(ak, aq[es], cA[st], 0, 0, 0);
            }
        }
    }
    __syncthreads();   // all waves done reading Kbuf0 before BODY(0) stages K[2]

    for (int t = 0; t < NT; t += 2) {
        PBODY(t,     cA, cB);
        PBODY(t + 1, cB, cA);
    }

    // ---- finalize per-lane l partial -> per-q total (one swap) ----
    l_run += __shfl_xor(l_run, 32);

    // ---- epilogue: flash-combine the two s-halves, then coalesced store ----
    float (*Part)[32][68] = (float (*)[32][68])smem;   // [4][32][68] = 34816 B
    if (halfId == 1) {
        #pragma unroll
        for (int dt = 0; dt < 2; ++dt)
            #pragma unroll
            for (int q4 = 0; q4 < 4; ++q4) {
                f32x4 v = (f32x4){osum[dt][q4 * 4], osum[dt][q4 * 4 + 1],
                                  osum[dt][q4 * 4 + 2], osum[dt][q4 * 4 + 3]};
                *(f32x4*)&Part[wq][c31][dt * 32 + q4 * 8 + hl * 4] = v;
            }
        if (hl == 0) {
            Part[wq][c31][64] = m_run;
            Part[wq][c31][65] = l_run;
        }
    }
    __syncthreads();
    if (halfId == 0) {
        const float m1 = Part[wq][c31][64];
        const float l1 = Part[wq][c31][65];
        const float m  = fmaxf(m_run, m1);
        const float s0 = EXP2(m_run - m);
        const float s1 = EXP2(m1 - m);
        const float inv = 1.0f / (l_run * s0 + l1 * s1);
        #pragma unroll
        for (int dt = 0; dt < 2; ++dt)
            #pragma unroll
            for (int q4 = 0; q4 < 4; ++q4) {
                f32x4 p1 = *(const f32x4*)&Part[wq][c31][dt * 32 + q4 * 8 + hl * 4];
                #pragma unroll
                for (int j = 0; j < 4; ++j)
                    osum[dt][q4 * 4 + j] = (osum[dt][q4 * 4 + j] * s0 + p1[j] * s1) * inv;
            }
    }
    __syncthreads();   // all Part reads done; smem reusable
    float (*Osm)[68] = (float (*)[68])smem;            // [128][68] = 34816 B
    if (halfId == 0) {
        #pragma unroll
        for (int dt = 0; dt < 2; ++dt)
            #pragma unroll
            for (int q4 = 0; q4 < 4; ++q4) {
                f32x4 v = (f32x4){osum[dt][q4 * 4], osum[dt][q4 * 4 + 1],
                                  osum[dt][q4 * 4 + 2], osum[dt][q4 * 4 + 3]};
                *(f32x4*)&Osm[wq * 32 + c31][dt * 32 + q4 * 8 + hl * 4] = v;
            }
    }
    __syncthreads();
    {
        float* ob = out + (((size_t)b * Ll + q0) * Hh + hd) * Dd;
        #pragma unroll
        for (int i = 0; i < 16; ++i) {
            const int r = wave * 16 + i;
            ob[(size_t)r * (Hh * Dd) + lane] = Osm[r][lane];
        }
    }
}

// ---------------------------- fallback (v1, verified r5) ----------------------------
__global__ __launch_bounds__(256)
void dsattn_fwd(const float* __restrict__ Q, const float* __restrict__ K,
                const float* __restrict__ V, const float* __restrict__ tau,
                const float* __restrict__ delta, float* __restrict__ out)
{
    __shared__ __align__(16) unsigned char Ksm[32 * 128];
    __shared__ __align__(16) unsigned char VTsm[64 * 80];
    __shared__ float dsm[32];
    __shared__ float Osm[4][16][68];

    const int tid  = threadIdx.x;
    const int wave = tid >> 6;
    const int lane = tid & 63;
    const int lq   = lane & 15;
    const int g    = lane >> 4;

    const int bh = blockIdx.y;
    const int b  = bh >> 4;
    const int h  = bh & 15;
    const int q0 = blockIdx.x * 64;

    const float alpha = 0.125f * tau[b];

    f16x8 aq[2];
    {
        const float* qp = Q + (((long)b * Ll + q0 + wave * 16 + lq) * Hh + h) * Ee;
        #pragma unroll
        for (int es = 0; es < 2; ++es) {
            const float* p = qp + es * 32 + g * 8;
            f16x8 t;
            #pragma unroll
            for (int j = 0; j < 8; ++j) t[j] = (_Float16)p[j];
            aq[es] = t;
        }
    }

    f32x4 osum[4];
    #pragma unroll
    for (int i = 0; i < 4; ++i) osum[i] = (f32x4){0.f, 0.f, 0.f, 0.f};
    float m_run = -1e30f, l_run = 0.0f;

    const float* kb = K + ((long)b * Ss * Hh + h) * Ee;
    const float* vb = V + ((long)b * Ss * Hh + h) * Dd;
    const float* db = delta + (long)b * Ss;

    const int kr    = tid >> 3;
    const int kc    = (tid & 7) * 8;
    const int kslot = (((tid & 7) ^ (kr & 7)) * 16);
    const int vd    = tid & 63;
    const int vsh   = tid >> 6;

    for (int sb = 0; sb < Ss; sb += 32) {
        __syncthreads();
        {
            const float* src = kb + (long)(sb + kr) * (Hh * Ee) + kc;
            f16x8 t;
            #pragma unroll
            for (int j = 0; j < 8; ++j) t[j] = (_Float16)src[j];
            *(f16x8*)(Ksm + kr * 128 + kslot) = t;
        }
        {
            const float* src = vb + (long)(sb + vsh * 8) * (Hh * Dd) + vd;
            f16x8 t;
            #pragma unroll
            for (int j = 0; j < 8; ++j) t[j] = (_Float16)src[j * (Hh * Dd)];
            *(f16x8*)(VTsm + vd * 80 + vsh * 16) = t;
        }
        if (tid < 32) dsm[tid] = 0.125f * db[sb + tid];
        __syncthreads();

        float p[8];
        float tmax = -1e30f;
        #pragma unroll
        for (int t = 0; t < 2; ++t) {
            f32x4 c = (f32x4){0.f, 0.f, 0.f, 0.f};
            #pragma unroll
            for (int es = 0; es < 2; ++es) {
                const int srow = t * 16 + lq;
                const int slot = ((es * 4 + g) ^ (srow & 7)) * 16;
                f16x8 ak = *(const f16x8*)(Ksm + srow * 128 + slot);
                c = __builtin_amdgcn_mfma_f32_16x16x32_f16(ak, aq[es], c, 0, 0, 0);
            }
            #pragma unroll
            for (int j = 0; j < 4; ++j) {
                float z = alpha * c[j] + dsm[t * 16 + 4 * g + j];
                p[t * 4 + j] = z;
                tmax = fmaxf(tmax, z);
            }
        }
        tmax = fmaxf(tmax, __shfl_xor(tmax, 16));
        tmax = fmaxf(tmax, __shfl_xor(tmax, 32));
        const float m_new = fmaxf(m_run, tmax);
        const float corr  = __expf(m_run - m_new);
        float psum = 0.f;
        #pragma unroll
        for (int i = 0; i < 8; ++i) { p[i] = __expf(p[i] - m_new); psum += p[i]; }
        psum += __shfl_xor(psum, 16);
        psum += __shfl_xor(psum, 32);
        l_run = l_run * corr + psum;
        m_run = m_new;
        #pragma unroll
        for (int dt = 0; dt < 4; ++dt)
            #pragma unroll
            for (int j = 0; j < 4; ++j)
                osum[dt][j] *= corr;

        Pk2 u00, u01, u10, u11;
        u00.h = __builtin_amdgcn_cvt_pkrtz(p[0], p[1]);
        u01.h = __builtin_amdgcn_cvt_pkrtz(p[2], p[3]);
        u10.h = __builtin_amdgcn_cvt_pkrtz(p[4], p[5]);
        u11.h = __builtin_amdgcn_cvt_pkrtz(p[6], p[7]);
        const int srcA = lq + 32 * (g & 1);
        const int srcB = srcA + 16;
        unsigned a00 = __shfl(u00.u, srcA), a01 = __shfl(u01.u, srcA);
        unsigned a10 = __shfl(u10.u, srcA), a11 = __shfl(u11.u, srcA);
        unsigned b00 = __shfl(u00.u, srcB), b01 = __shfl(u01.u, srcB);
        unsigned b10 = __shfl(u10.u, srcB), b11 = __shfl(u11.u, srcB);
        const bool hi = (g >= 2);
        PackU bp;
        bp.u[0] = hi ? a10 : a00;
        bp.u[1] = hi ? a11 : a01;
        bp.u[2] = hi ? b10 : b00;
        bp.u[3] = hi ? b11 : b01;

        #pragma unroll
        for (int dt = 0; dt < 4; ++dt) {
            f16x8 av = *(const f16x8*)(VTsm + (dt * 16 + lq) * 80 + g * 16);
            osum[dt] = __builtin_amdgcn_mfma_f32_16x16x32_f16(av, bp.v, osum[dt], 0, 0, 0);
        }
    }

    const float inv = 1.0f / l_run;
    #pragma unroll
    for (int dt = 0; dt < 4; ++dt)
        #pragma unroll
        for (int j = 0; j < 4; ++j)
            Osm[wave][lq][dt * 16 + 4 * g + j] = osum[dt][j] * inv;
    __syncthreads();
    {
        float* ob = out + (((long)b * Ll + q0 + wave * 16) * Hh + h) * Dd;
        #pragma unroll
        for (int r = 0; r < 16; ++r)
            ob[(long)r * (Hh * Dd) + lane] = Osm[wave][r][lane];
    }
}

extern "C" void kernel_launch(void* const* d_in, const int* in_sizes, int n_in,
                              void* d_out, int out_size, void* d_ws, size_t ws_size,
                              hipStream_t stream) {
    const float* Q     = (const float*)d_in[0];
    const float* K     = (const float*)d_in[1];
    const float* V     = (const float*)d_in[2];
    const float* tau   = (const float*)d_in[3];
    const float* delta = (const float*)d_in[4];
    float* out = (float*)d_out;

    const size_t elems = (size_t)Bb * Hh * Ss * Ee;            // 4M per tensor
    const size_t need  = elems * 2 * 2 + (size_t)Bb * Ss * 4;  // K16 + VT16 + delta2

    if (ws_size >= need) {
        _Float16* K16    = (_Float16*)d_ws;
        _Float16* VT16   = K16 + elems;
        float*    delta2 = (float*)(VT16 + elems);
        hipLaunchKernelGGL(prepass_k, dim3(elems / 4 / 256), dim3(256), 0, stream,
                           K, K16, delta, delta2);
        hipLaunchKernelGGL(prepass_v, dim3(Ss / 64, Bb * Hh), dim3(256), 0, stream, V, VT16);
        hipLaunchKernelGGL(dsattn_fwd_v10, dim3(512), dim3(512), 65536, stream,
                           Q, K16, VT16, tau, delta2, out);
    } else {
        hipLaunchKernelGGL(dsattn_fwd, dim3(Ll / 64, Bb * Hh), dim3(256), 0, stream,
                           Q, K, V, tau, delta, out);
    }
}